// Round 14
// baseline (310.021 us; speedup 1.0000x reference)
//
#include <hip/hip_runtime.h>
#include <hip/hip_bf16.h>
#include <stdint.h>

#define M_DIM 8192
#define N_DIM 4096
#define K_DIM 4096
#define BM 256
#define BN 256
#define BK 64
#define NT (K_DIM / BK)    // 64 K-tiles
#define THREADS 512
#define NBLOCKS_VQ (N_DIM * K_DIM / 16)

#define ATILE 32768        // one A (or B) K-tile: 256 x 64 x 2B
#define BREG  65536        // B region base
#define SMEM_BYTES 131072

typedef short bf16x8 __attribute__((ext_vector_type(8)));
typedef float f32x16 __attribute__((ext_vector_type(16)));
typedef unsigned short ushort_t;
typedef ushort_t ushort8 __attribute__((ext_vector_type(8)));

#define GLOBAL_AS __attribute__((address_space(1)))
#define LDS_AS __attribute__((address_space(3)))

__device__ __forceinline__ ushort_t f2bf(float f) {
  union { float f; uint32_t u; } v; v.f = f;
  uint32_t u = v.u;
  return (ushort_t)((u + 0x7FFFu + ((u >> 16) & 1u)) >> 16);
}

// ---------------- dequant: W[j][k] = coarse[cl[b]] + res[rl[b]], block b of 16
__global__ __launch_bounds__(256) void dequant_w(
    const float* __restrict__ cc, const int* __restrict__ cl,
    const float* __restrict__ rc, const int* __restrict__ rl,
    ushort_t* __restrict__ wout) {
  int b = blockIdx.x * 256 + threadIdx.x;
  int ci = cl[b];
  int ri = rl[b];
  const float4* c4 = (const float4*)(cc + (size_t)ci * 16);
  const float4* r4 = (const float4*)(rc + (size_t)ri * 16);
  float s[16];
#pragma unroll
  for (int p = 0; p < 4; ++p) {
    float4 a = c4[p];
    float4 r = r4[p];
    s[p * 4 + 0] = a.x + r.x;
    s[p * 4 + 1] = a.y + r.y;
    s[p * 4 + 2] = a.z + r.z;
    s[p * 4 + 3] = a.w + r.w;
  }
  ushort8 o0, o1;
#pragma unroll
  for (int j = 0; j < 8; ++j) o0[j] = f2bf(s[j]);
#pragma unroll
  for (int j = 0; j < 8; ++j) o1[j] = f2bf(s[8 + j]);
  ushort8* dst = (ushort8*)(wout + (size_t)b * 16);
  dst[0] = o0;
  dst[1] = o1;
}

// ---------------- x fp32 -> bf16
__global__ __launch_bounds__(256) void cvt_x_bf16(const float* __restrict__ x,
                                                  ushort_t* __restrict__ xb) {
  size_t i = (size_t)blockIdx.x * 256 + threadIdx.x;
  const float4* p = (const float4*)x + i * 2;
  float4 a = p[0];
  float4 b = p[1];
  ushort8 o;
  o[0] = f2bf(a.x); o[1] = f2bf(a.y); o[2] = f2bf(a.z); o[3] = f2bf(a.w);
  o[4] = f2bf(b.x); o[5] = f2bf(b.y); o[6] = f2bf(b.z); o[7] = f2bf(b.w);
  ((ushort8*)xb)[i] = o;
}

// ---------------- staging state
struct SP {
  const ushort_t* gA;  // per-thread A source (tile 0, inverse-swizzled col)
  const ushort_t* gB;  // per-thread B source (tile 0, inverse-swizzled col)
  char* sm;
  int wuni;            // wave*1024 (wave-uniform LDS offset; HW appends lane*16)
};

__device__ __forceinline__ void stA(const SP& s, int r, int tile, int dbuf) {
  __builtin_amdgcn_global_load_lds(
      (const GLOBAL_AS void*)(s.gA + (size_t)tile * BK + (size_t)r * 64 * K_DIM),
      (LDS_AS void*)(s.sm + dbuf * ATILE + r * 8192 + s.wuni), 16, 0, 0);
}
__device__ __forceinline__ void stB(const SP& s, int r, int tile, int dbuf) {
  __builtin_amdgcn_global_load_lds(
      (const GLOBAL_AS void*)(s.gB + (size_t)tile * BK + (size_t)r * 64 * K_DIM),
      (LDS_AS void*)(s.sm + BREG + dbuf * ATILE + r * 8192 + s.wuni), 16, 0, 0);
}
// half-tiles: A-half h = rounds {2h, 2h+1} (rows h*128..h*128+127); same for B
__device__ __forceinline__ void stAh(const SP& s, int h, int tile, int dbuf) {
  stA(s, 2 * h, tile, dbuf); stA(s, 2 * h + 1, tile, dbuf);
}
__device__ __forceinline__ void stBh(const SP& s, int h, int tile, int dbuf) {
  stB(s, 2 * h, tile, dbuf); stB(s, 2 * h + 1, tile, dbuf);
}

#define BAR()   __builtin_amdgcn_s_barrier()
#define SCB()   __builtin_amdgcn_sched_barrier(0)
#define LGKM0() do { asm volatile("s_waitcnt lgkmcnt(0)" ::: "memory"); SCB(); } while (0)
#define LGKM8() asm volatile("s_waitcnt lgkmcnt(8)" ::: "memory")
#define VMC(n)  asm volatile("s_waitcnt vmcnt(" #n ")" ::: "memory")

#define MFMA32(A_, B_, C_) \
  C_ = __builtin_amdgcn_mfma_f32_32x32x16_bf16(A_, B_, C_, 0, 0, 0)

// 8 MFMAs of one (m-half, n-block) quadrant: kk outer, mb inner
#define MFMA_Q(AARR, BARR, M0)                                \
  __builtin_amdgcn_s_setprio(1);                              \
  _Pragma("unroll")                                           \
  for (int kk = 0; kk < 4; ++kk)                              \
    _Pragma("unroll")                                         \
    for (int mb = 0; mb < 2; ++mb)                            \
      MFMA32(AARR[mb][kk], BARR[kk], acc[M0 + mb][NB_]);      \
  __builtin_amdgcn_s_setprio(0);

// m201-faithful 4-phase K-tile (32x32x16). Phase = {ds_reads, stage 1 HT,
// [lgkm8], [VMC@ph4], BAR, lgkm0, setprio 8-MFMA, BAR}. Stage stream:
// ph1->A0(t+1), ph2->A1(t+1), ph3->B0(t+2), ph4->B1(t+2); vmcnt(4)@ph4
// certifies exactly tile t+1's 4 half-tiles, leaves t+2's B halves in flight.
template<int ST>   // 2 = full stage, 1 = A-halves of t+1 only + drain, 0 = none
__device__ __forceinline__ void ktile(const SP& sp, int buf, int t,
    int aBase, int bBase, const int (&off)[4], f32x16 (&acc)[4][2]) {
  const ushort_t* bufA = (const ushort_t*)(sp.sm + buf * ATILE);
  const ushort_t* bufB = (const ushort_t*)(sp.sm + BREG + buf * ATILE);
  bf16x8 a[2][4], a2[2][4], b0[4], b1[4];

  // ---- phase 1: reads A-mh0 (8) + B-n0 (4); MFMA (mh0, n0)
#pragma unroll
  for (int mb = 0; mb < 2; ++mb)
#pragma unroll
    for (int kk = 0; kk < 4; ++kk)
      a[mb][kk] = *(const bf16x8*)(bufA + aBase + mb * 2048 + off[kk]);
#pragma unroll
  for (int kk = 0; kk < 4; ++kk)
    b0[kk] = *(const bf16x8*)(bufB + bBase + off[kk]);
  if constexpr (ST == 2 || ST == 1) stAh(sp, 0, t + 1, buf ^ 1);
  LGKM8();
  BAR(); LGKM0();
  { const int NB_ = 0; MFMA_Q(a, b0, 0); }
  BAR(); SCB();

  // ---- phase 2: reads B-n1 (4); MFMA (mh0, n1)
#pragma unroll
  for (int kk = 0; kk < 4; ++kk)
    b1[kk] = *(const bf16x8*)(bufB + bBase + 2048 + off[kk]);
  if constexpr (ST == 2 || ST == 1) stAh(sp, 1, t + 1, buf ^ 1);
  BAR(); LGKM0();
  { const int NB_ = 1; MFMA_Q(a, b1, 0); }
  BAR(); SCB();

  // ---- phase 3: reads A-mh1 (8); MFMA (mh1, n0)
#pragma unroll
  for (int mb = 0; mb < 2; ++mb)
#pragma unroll
    for (int kk = 0; kk < 4; ++kk)
      a2[mb][kk] = *(const bf16x8*)(bufA + aBase + (2 + mb) * 2048 + off[kk]);
  if constexpr (ST == 2) stBh(sp, 0, t + 2, buf);
  LGKM8();
  BAR(); LGKM0();
  { const int NB_ = 0; MFMA_Q(a2, b0, 2); }
  BAR(); SCB();

  // ---- phase 4: no reads; MFMA (mh1, n1); the tile's single vmcnt
  if constexpr (ST == 2) { stBh(sp, 1, t + 2, buf); SCB(); VMC(4); }
  else if constexpr (ST == 1) { SCB(); VMC(0); }
  BAR();
  { const int NB_ = 1; MFMA_Q(a2, b1, 2); }
  BAR(); SCB();
}

// C[M][N] = A[M][K] * B[N][K]^T + bias; 256x256, BK=64, 32x32x16, m201 schedule
// LDS swizzle key = (row>>2)&7 (phase-spread: same-slot lanes differ in lane&3)
__global__ __launch_bounds__(THREADS, 2) void gemm_bf16(
    const ushort_t* __restrict__ A, const ushort_t* __restrict__ B,
    const float* __restrict__ bias, float* __restrict__ C) {
  extern __shared__ char smem[];

  const int nwg = (M_DIM / BM) * (N_DIM / BN);  // 512, %8==0 -> bijective
  int bid = blockIdx.x;
  int swz = (bid & 7) * (nwg >> 3) + (bid >> 3);
  int bx = swz & 15;
  int by = swz >> 4;
  const int tileM = by * BM;
  const int tileN = bx * BN;

  const int tid = threadIdx.x;
  const int lane = tid & 63;
  const int wave = tid >> 6;
  const int wrM = wave >> 2;    // 0..1 -> M offset wrM*128
  const int wcN = wave & 3;     // 0..3 -> N offset wcN*64

  // ---- staging source addressing: 16B-slot ^= (row>>2)&7 (inverse on src);
  // absolute row = r*64 + q, and 64 ≡ 0 mod 32 -> key = (q>>2)&7, round-indep.
  int q = tid >> 3;             // row within a 64-row round
  int slot = tid & 7;
  int scol = ((slot ^ ((q >> 2) & 7)) << 3);
  SP sp;
  sp.sm = smem;
  sp.wuni = wave << 10;
  sp.gA = A + (size_t)(tileM + q) * K_DIM + scol;
  sp.gB = B + (size_t)(tileN + q) * K_DIM + scol;

  // ---- 32x32x16 fragment addressing (R11-verified layout): row = base+(lane&31),
  // k = kk*16 + (lane>>5)*8 + j; swizzled 16B-slot = (2kk|l5) ^ ((row>>2)&7).
  // mb/nb/wcN row offsets all ≡ 0 mod 32 -> key = (l31>>2)&7 for every frag.
  const int l31 = lane & 31;
  const int l5 = lane >> 5;
  const int key = (l31 >> 2) & 7;
  int off[4];
#pragma unroll
  for (int kk = 0; kk < 4; ++kk)
    off[kk] = ((((kk << 1) | l5) ^ key) << 3);
  const int aBase = (wrM * 128 + l31) * 64;   // mb adds 2048 (32 rows x 64)
  const int bBase = (wcN * 64 + l31) * 64;    // nb adds 2048

  f32x16 acc[4][2];
#pragma unroll
  for (int m = 0; m < 4; ++m)
#pragma unroll
    for (int n = 0; n < 2; ++n) acc[m][n] = (f32x16)0.0f;

  // ---- prologue: tile0 {B0,B1,A0,A1} + tile1 {B0,B1}; certify tile0
  stBh(sp, 0, 0, 0); stBh(sp, 1, 0, 0);
  stAh(sp, 0, 0, 0); stAh(sp, 1, 0, 0);
  stBh(sp, 0, 1, 1); stBh(sp, 1, 1, 1);
  SCB(); VMC(4); BAR(); SCB();

  for (int t = 0; t < NT - 2; ++t)
    ktile<2>(sp, t & 1, t, aBase, bBase, off, acc);
  ktile<1>(sp, (NT - 2) & 1, NT - 2, aBase, bBase, off, acc);
  ktile<0>(sp, (NT - 1) & 1, NT - 1, aBase, bBase, off, acc);

  // ---- epilogue: 32x32 C/D layout col=lane&31, row=(r&3)+8*(r>>2)+4*(lane>>5)
  const int orow0 = tileM + wrM * 128 + 4 * l5;
  const int ocol0 = tileN + wcN * 64 + l31;
#pragma unroll
  for (int mb = 0; mb < 4; ++mb) {
#pragma unroll
    for (int nb = 0; nb < 2; ++nb) {
      int col = ocol0 + nb * 32;
      float bv = bias[col];
#pragma unroll
      for (int r2 = 0; r2 < 16; ++r2) {
        int row = orow0 + mb * 32 + (r2 & 3) + 8 * (r2 >> 2);
        C[(size_t)row * N_DIM + col] = acc[mb][nb][r2] + bv;
      }
    }
  }
}

extern "C" void kernel_launch(void* const* d_in, const int* in_sizes, int n_in,
                              void* d_out, int out_size, void* d_ws, size_t ws_size,
                              hipStream_t stream) {
  const float* x = (const float*)d_in[0];
  const float* cc = (const float*)d_in[1];
  const int* cl = (const int*)d_in[2];
  const float* rc = (const float*)d_in[3];
  const int* rl = (const int*)d_in[4];
  const float* bias = (const float*)d_in[5];
  float* out = (float*)d_out;

  ushort_t* Wbf = (ushort_t*)d_ws;                                  // 32 MB
  ushort_t* Xbf = (ushort_t*)d_ws + (size_t)N_DIM * K_DIM;          // 64 MB

  (void)hipFuncSetAttribute((const void*)gemm_bf16,
                            hipFuncAttributeMaxDynamicSharedMemorySize, SMEM_BYTES);

  dequant_w<<<NBLOCKS_VQ / 256, 256, 0, stream>>>(cc, cl, rc, rl, Wbf);
  cvt_x_bf16<<<(int)((M_DIM * (size_t)K_DIM / 8) / 256), 256, 0, stream>>>(x, Xbf);
  gemm_bf16<<<(M_DIM / BM) * (N_DIM / BN), THREADS, SMEM_BYTES, stream>>>(Xbf, Wbf, bias, out);
}

// Round 15
// 268.881 us; speedup vs baseline: 1.1530x; 1.1530x over previous
//
#include <hip/hip_runtime.h>
#include <hip/hip_bf16.h>
#include <stdint.h>

#define M_DIM 8192
#define N_DIM 4096
#define K_DIM 4096
#define BM 256
#define BN 256
#define BK 64
#define NT (K_DIM / BK)    // 64 K-tiles
#define THREADS 512
#define NBLOCKS_VQ (N_DIM * K_DIM / 16)

#define ATILE 32768        // one A (or B) K-tile: 256 x 64 x 2B
#define BREG  65536        // B region base
#define SMEM_BYTES 131072

typedef short bf16x8 __attribute__((ext_vector_type(8)));
typedef float f32x4 __attribute__((ext_vector_type(4)));
typedef unsigned short ushort_t;
typedef ushort_t ushort8 __attribute__((ext_vector_type(8)));

#define GLOBAL_AS __attribute__((address_space(1)))
#define LDS_AS __attribute__((address_space(3)))

__device__ __forceinline__ ushort_t f2bf(float f) {
  union { float f; uint32_t u; } v; v.f = f;
  uint32_t u = v.u;
  return (ushort_t)((u + 0x7FFFu + ((u >> 16) & 1u)) >> 16);
}

// ---------------- dequant: W[j][k] = coarse[cl[b]] + res[rl[b]], block b of 16
__global__ __launch_bounds__(256) void dequant_w(
    const float* __restrict__ cc, const int* __restrict__ cl,
    const float* __restrict__ rc, const int* __restrict__ rl,
    ushort_t* __restrict__ wout) {
  int b = blockIdx.x * 256 + threadIdx.x;
  int ci = cl[b];
  int ri = rl[b];
  const float4* c4 = (const float4*)(cc + (size_t)ci * 16);
  const float4* r4 = (const float4*)(rc + (size_t)ri * 16);
  float s[16];
#pragma unroll
  for (int p = 0; p < 4; ++p) {
    float4 a = c4[p];
    float4 r = r4[p];
    s[p * 4 + 0] = a.x + r.x;
    s[p * 4 + 1] = a.y + r.y;
    s[p * 4 + 2] = a.z + r.z;
    s[p * 4 + 3] = a.w + r.w;
  }
  ushort8 o0, o1;
#pragma unroll
  for (int j = 0; j < 8; ++j) o0[j] = f2bf(s[j]);
#pragma unroll
  for (int j = 0; j < 8; ++j) o1[j] = f2bf(s[8 + j]);
  ushort8* dst = (ushort8*)(wout + (size_t)b * 16);
  dst[0] = o0;
  dst[1] = o1;
}

// ---------------- x fp32 -> bf16
__global__ __launch_bounds__(256) void cvt_x_bf16(const float* __restrict__ x,
                                                  ushort_t* __restrict__ xb) {
  size_t i = (size_t)blockIdx.x * 256 + threadIdx.x;
  const float4* p = (const float4*)x + i * 2;
  float4 a = p[0];
  float4 b = p[1];
  ushort8 o;
  o[0] = f2bf(a.x); o[1] = f2bf(a.y); o[2] = f2bf(a.z); o[3] = f2bf(a.w);
  o[4] = f2bf(b.x); o[5] = f2bf(b.y); o[6] = f2bf(b.z); o[7] = f2bf(b.w);
  ((ushort8*)xb)[i] = o;
}

// ---------------- staging state
struct SP {
  const ushort_t* gA;  // per-thread A source (tile 0, inverse-swizzled col)
  const ushort_t* gB;  // per-thread B source (tile 0, permuted row, swz col)
  char* sm;
  int wuni;            // wave*1024 (wave-uniform LDS offset; HW appends lane*16)
};

__device__ __forceinline__ void stA(const SP& s, int r, int tile, int dbuf) {
  __builtin_amdgcn_global_load_lds(
      (const GLOBAL_AS void*)(s.gA + (size_t)tile * BK + (size_t)r * 64 * K_DIM),
      (LDS_AS void*)(s.sm + dbuf * ATILE + r * 8192 + s.wuni), 16, 0, 0);
}
__device__ __forceinline__ void stB(const SP& s, int r, int tile, int dbuf) {
  // LDS B row order is n-half-major: round r covers these global row offsets
  constexpr int roff[4] = {0, 128, 32, 160};
  __builtin_amdgcn_global_load_lds(
      (const GLOBAL_AS void*)(s.gB + (size_t)tile * BK + (size_t)roff[r] * K_DIM),
      (LDS_AS void*)(s.sm + BREG + dbuf * ATILE + r * 8192 + s.wuni), 16, 0, 0);
}

#define BAR()   __builtin_amdgcn_s_barrier()
#define SCB()   __builtin_amdgcn_sched_barrier(0)
#define VMC(n)  asm volatile("s_waitcnt vmcnt(" #n ")" ::: "memory")
#define LGKM(n) asm volatile("s_waitcnt lgkmcnt(" #n ")" ::: "memory")

#define MFMA_Q(ACCM, AARR, BARR, ACCN)                                           \
  __builtin_amdgcn_s_setprio(1);                                                 \
  _Pragma("unroll")                                                              \
  for (int m = 0; m < 4; ++m)                                                    \
    _Pragma("unroll")                                                            \
    for (int ni = 0; ni < 2; ++ni) {                                             \
      acc[ACCM + m][ACCN + ni] = __builtin_amdgcn_mfma_f32_16x16x32_bf16(        \
          AARR[m * 2 + 0], BARR[ni * 2 + 0], acc[ACCM + m][ACCN + ni], 0, 0, 0); \
      acc[ACCM + m][ACCN + ni] = __builtin_amdgcn_mfma_f32_16x16x32_bf16(        \
          AARR[m * 2 + 1], BARR[ni * 2 + 1], acc[ACCM + m][ACCN + ni], 0, 0, 0); \
    }                                                                            \
  __builtin_amdgcn_s_setprio(0);

// Counted-lgkm pipelined K-tile (T4 applied to the LDS pipe):
// {VMC(0) [DMAs are 1 tile old -> non-blocking] -> BAR -> 8 DMA(t+1) ->
//  24 ds_reads in consumption order A0|B0|B1|A1 (SCB-pinned groups) ->
//  lgkm(12) Q1 -> lgkm(8) Q2 -> lgkm(0) Q3,Q4}.
// Q1 starts when only its 12 reads are done; B1+A1 stream under Q1/Q2 MFMAs.
// global_load_lds counts vmcnt ONLY, so mid-tile lgkm waits never drain DMA.
// Cross-wave safety: a wave's tile-t reads are lgkm-complete before its Q3/Q4,
// hence before its t+1-top barrier; overwrite of buf comes after that barrier.
template<bool ISSUE>
__device__ __forceinline__ void ktile(const SP& sp, int buf, int t,
    int aBase, int bBase, int sw0, int sw1, f32x4 (&acc)[8][4]) {
  const ushort_t* bufA = (const ushort_t*)(sp.sm + buf * ATILE);
  const ushort_t* bufB = (const ushort_t*)(sp.sm + BREG + buf * ATILE);
  bf16x8 a0[8], a1[8], b0[4], b1[4];

  SCB(); VMC(0); BAR(); SCB();

  if constexpr (ISSUE) {
    stA(sp, 0, t + 1, buf ^ 1); stA(sp, 1, t + 1, buf ^ 1);
    stA(sp, 2, t + 1, buf ^ 1); stA(sp, 3, t + 1, buf ^ 1);
    stB(sp, 0, t + 1, buf ^ 1); stB(sp, 1, t + 1, buf ^ 1);
    stB(sp, 2, t + 1, buf ^ 1); stB(sp, 3, t + 1, buf ^ 1);
  }

  // ---- reads, consumption order; SCB pins group order so lgkm counts hold
#pragma unroll
  for (int m = 0; m < 4; ++m) {
    a0[m * 2 + 0] = *(const bf16x8*)(bufA + aBase + m * 1024 + sw0);
    a0[m * 2 + 1] = *(const bf16x8*)(bufA + aBase + m * 1024 + sw1);
  }
  SCB();
#pragma unroll
  for (int ni = 0; ni < 2; ++ni) {
    b0[ni * 2 + 0] = *(const bf16x8*)(bufB + bBase + ni * 1024 + sw0);
    b0[ni * 2 + 1] = *(const bf16x8*)(bufB + bBase + ni * 1024 + sw1);
  }
  SCB();
#pragma unroll
  for (int ni = 0; ni < 2; ++ni) {
    b1[ni * 2 + 0] = *(const bf16x8*)(bufB + bBase + 8192 + ni * 1024 + sw0);
    b1[ni * 2 + 1] = *(const bf16x8*)(bufB + bBase + 8192 + ni * 1024 + sw1);
  }
  SCB();
#pragma unroll
  for (int m = 0; m < 4; ++m) {
    a1[m * 2 + 0] = *(const bf16x8*)(bufA + aBase + 4096 + m * 1024 + sw0);
    a1[m * 2 + 1] = *(const bf16x8*)(bufA + aBase + 4096 + m * 1024 + sw1);
  }
  SCB();

  LGKM(12);  // A0+B0 (first 12) complete; B1+A1 may stay in flight
  SCB();
  MFMA_Q(0, a0, b0, 0);
  LGKM(8);   // + B1 complete
  SCB();
  MFMA_Q(0, a0, b1, 2);
  LGKM(0);   // + A1 complete (ds-only)
  SCB();
  MFMA_Q(4, a1, b0, 0);
  MFMA_Q(4, a1, b1, 2);
}

// C[M][N] = A[M][K] * B[N][K]^T + bias; 256x256, BK=64, counted-lgkm pipeline
__global__ __launch_bounds__(THREADS, 2) void gemm_bf16(
    const ushort_t* __restrict__ A, const ushort_t* __restrict__ B,
    const float* __restrict__ bias, float* __restrict__ C) {
  extern __shared__ char smem[];

  const int nwg = (M_DIM / BM) * (N_DIM / BN);  // 512, %8==0 -> bijective
  int bid = blockIdx.x;
  int swz = (bid & 7) * (nwg >> 3) + (bid >> 3);
  int bx = swz & 15;
  int by = swz >> 4;
  const int tileM = by * BM;
  const int tileN = bx * BN;

  const int tid = threadIdx.x;
  const int lane = tid & 63;
  const int wave = tid >> 6;
  const int wrM = wave >> 2;    // 0..1 -> M offset wrM*128
  const int wcN = wave & 3;     // 0..3 -> N offset wcN*64

  // ---- staging source addressing (swizzle: 16B-slot ^= row&7, inverse on src)
  int q = tid >> 3;             // row within a 64-row round
  int slot = tid & 7;
  int scol = ((slot ^ (q & 7)) << 3);
  SP sp;
  sp.sm = smem;
  sp.wuni = wave << 10;
  sp.gA = A + (size_t)(tileM + q) * K_DIM + scol;
  // B row permutation (n-half-major): round base row = (q>>5)*64 + (q&31)
  int rB0 = ((q >> 5) << 6) + (q & 31);
  sp.gB = B + (size_t)(tileN + rB0) * K_DIM + scol;

  // ---- fragment read offsets: slot(kk,g) = ((kk*4+g) ^ (lrow&7)), elems=slot*8
  const int lrow = lane & 15;
  const int g = lane >> 4;
  const int l7 = lane & 7;
  const int sw0 = ((g ^ l7) << 3);
  const int sw1 = (((4 + g) ^ l7) << 3);
  const int aBase = (wrM * 128 + lrow) * 64;   // mh adds 4096, m adds 1024
  const int bBase = (wcN * 32 + lrow) * 64;    // nh adds 8192, ni adds 1024

  f32x4 acc[8][4];
#pragma unroll
  for (int m = 0; m < 8; ++m)
#pragma unroll
    for (int n = 0; n < 4; ++n) acc[m][n] = (f32x4)0.0f;

  // ---- prologue: stage tile 0 into buf0 (tile-top VMC(0) certifies it)
  stA(sp, 0, 0, 0); stA(sp, 1, 0, 0); stA(sp, 2, 0, 0); stA(sp, 3, 0, 0);
  stB(sp, 0, 0, 0); stB(sp, 1, 0, 0); stB(sp, 2, 0, 0); stB(sp, 3, 0, 0);

  for (int t = 0; t < NT - 1; ++t)
    ktile<true>(sp, t & 1, t, aBase, bBase, sw0, sw1, acc);
  ktile<false>(sp, (NT - 1) & 1, NT - 1, aBase, bBase, sw0, sw1, acc);

  // ---- epilogue: C/D layout col = lane&15, row = (lane>>4)*4 + reg
  const int orow = tileM + wrM * 128 + ((lane >> 4) << 2);
  const int ocol0 = tileN + wcN * 64 + lrow;
  float bv[4];
#pragma unroll
  for (int n = 0; n < 4; ++n) bv[n] = bias[ocol0 + n * 16];
#pragma unroll
  for (int m = 0; m < 8; ++m) {
#pragma unroll
    for (int n = 0; n < 4; ++n) {
      size_t base = (size_t)(orow + m * 16) * N_DIM + (ocol0 + n * 16);
#pragma unroll
      for (int r = 0; r < 4; ++r)
        C[base + (size_t)r * N_DIM] = acc[m][n][r] + bv[n];
    }
  }
}

extern "C" void kernel_launch(void* const* d_in, const int* in_sizes, int n_in,
                              void* d_out, int out_size, void* d_ws, size_t ws_size,
                              hipStream_t stream) {
  const float* x = (const float*)d_in[0];
  const float* cc = (const float*)d_in[1];
  const int* cl = (const int*)d_in[2];
  const float* rc = (const float*)d_in[3];
  const int* rl = (const int*)d_in[4];
  const float* bias = (const float*)d_in[5];
  float* out = (float*)d_out;

  ushort_t* Wbf = (ushort_t*)d_ws;                                  // 32 MB
  ushort_t* Xbf = (ushort_t*)d_ws + (size_t)N_DIM * K_DIM;          // 64 MB

  (void)hipFuncSetAttribute((const void*)gemm_bf16,
                            hipFuncAttributeMaxDynamicSharedMemorySize, SMEM_BYTES);

  dequant_w<<<NBLOCKS_VQ / 256, 256, 0, stream>>>(cc, cl, rc, rl, Wbf);
  cvt_x_bf16<<<(int)((M_DIM * (size_t)K_DIM / 8) / 256), 256, 0, stream>>>(x, Xbf);
  gemm_bf16<<<(M_DIM / BM) * (N_DIM / BN), THREADS, SMEM_BYTES, stream>>>(Xbf, Wbf, bias, out);
}